// Round 8
// baseline (138.715 us; speedup 1.0000x reference)
//
#include <hip/hip_runtime.h>

// LightGlue attention block: B=4, N=4096, D=256.
//   q = desc0@Wq^T+bq; k,v = desc1@{Wk,Wv}^T+{bk,bv}
//   att = softmax(q k^T / 16) v ; out = att@Wo^T + bo
// ws layout (bytes):
//   q     [0,        8M)   bf16 [b][n][d] row-major
//   k     [8M,      16M)   bf16 [b][n][d] row-major (64-row tiles contiguous 32KB)
//   v     [16M,     24M)   bf16 BLOCKED [b][kkb 64][d 256][kk 64]
//   part0 [24M,     32M)   bf16 [q 16384][d 256]  (UNNORMALIZED O partial)
//   part1 [32M,     40M)   bf16 [q 16384][d 256]
//   lw    [40M, 40M+128K)  f32  [2][16384]
//   wbf   [42074112, +512K) bf16 Wq|Wk|Wv|Wo row-major [n 256][k 256]

typedef __attribute__((ext_vector_type(8))) __bf16 bf16x8;
typedef __attribute__((ext_vector_type(4))) float f32x4;
typedef __attribute__((ext_vector_type(16))) float f32x16;
typedef __attribute__((ext_vector_type(4))) unsigned int u32x4;
typedef __attribute__((ext_vector_type(2))) unsigned int u32x2;
typedef __attribute__((ext_vector_type(4))) unsigned short us16x4;

__device__ __forceinline__ unsigned short f2bf(float f) {
  unsigned u = __builtin_bit_cast(unsigned, f);
  u += 0x7FFFu + ((u >> 16) & 1u);  // RNE
  return (unsigned short)(u >> 16);
}
__device__ __forceinline__ unsigned pk2(float a, float b) {
  return (unsigned)f2bf(a) | ((unsigned)f2bf(b) << 16);
}
__device__ __forceinline__ unsigned cvtpk(float lo, float hi) {
  unsigned r;
  asm("v_cvt_pk_bf16_f32 %0, %1, %2" : "=v"(r) : "v"(lo), "v"(hi));
  return r;
}
__device__ __forceinline__ float bf2f(unsigned short s) {
  return __builtin_bit_cast(float, ((unsigned)s) << 16);
}
__device__ __forceinline__ bf16x8 ldbf16(const void* p) {
  return __builtin_bit_cast(bf16x8, *(const u32x4*)p);
}
__device__ __forceinline__ f32x4 mfma16(bf16x8 a, bf16x8 b, f32x4 c) {
  return __builtin_amdgcn_mfma_f32_16x16x32_bf16(a, b, c, 0, 0, 0);
}
__device__ __forceinline__ f32x16 mfma32(bf16x8 a, bf16x8 b, f32x16 c) {
  return __builtin_amdgcn_mfma_f32_32x32x16_bf16(a, b, c, 0, 0, 0);
}
__device__ __forceinline__ void gld16(void* lds, const void* gsrc) {
  __builtin_amdgcn_global_load_lds(
      (const __attribute__((address_space(1))) unsigned int*)gsrc,
      (__attribute__((address_space(3))) unsigned int*)lds, 16, 0, 0);
}

// ---------------- W convert: 4x [256][256] f32 -> bf16 row-major ----------------
__global__ __launch_bounds__(256, 8) void wconv_k(const float* __restrict__ w0,
                                                  const float* __restrict__ w1,
                                                  const float* __restrict__ w2,
                                                  const float* __restrict__ w3,
                                                  unsigned short* __restrict__ out) {
  const int b = blockIdx.x, t = threadIdx.x;
  const int wi = b >> 5;
  const float* src = wi == 0 ? w0 : wi == 1 ? w1 : wi == 2 ? w2 : w3;
  const int idx = ((b & 31) * 256 + t) * 8;
  float4 x = *(const float4*)(src + idx), y = *(const float4*)(src + idx + 4);
  u32x4 v;
  v[0] = pk2(x.x, x.y); v[1] = pk2(x.z, x.w);
  v[2] = pk2(y.x, y.y); v[3] = pk2(y.z, y.w);
  *(u32x4*)(out + (size_t)wi * 65536 + idx) = v;
}

// ---------------- projection GEMM: C[16384,256] = A @ W^T + bias ----------------
// Grid 256 (1 block/CU): M-tile 64, full N=256. 512 thr (8 waves = 4 rt x 2 ch2).
// W: bf16 (pre-converted), staged via gld16 dbuf [256 col][32 k] per chunk.
// A: staged f32->bf16 (or part-merge) [64 row][32 k] per chunk, T14 split.
// IN_MODE: 0 = A f32 desc; 2 = A = (part0+part1)*inv; 3 = A = part0*inv.
// MODE: 0 bf16 row-major (SWAPPED mfma: regs = 4 consecutive cols -> 8B stores);
//       1 bf16 V-BLOCKED [b][n>>6][col][n&63] (unswapped: regs = 4 consecutive n);
//       2 f32 row-major (swapped -> float4 stores).
template <int IN_MODE, int MODE>
__global__ __launch_bounds__(512, 2) void proj_k(const void* __restrict__ Ain,
                                                 const unsigned short* __restrict__ Wb,
                                                 const float* __restrict__ bias,
                                                 void* __restrict__ Cout,
                                                 const float* __restrict__ lwA) {
  __shared__ __align__(16) unsigned short Al[2][64 * 32];
  __shared__ __align__(16) unsigned short Wl[2][256 * 32];
  __shared__ float biasl[256];
  const int tid = threadIdx.x, w = tid >> 6, l = tid & 63, g = l >> 4, c = l & 15;
  const int rt = w >> 1, ch2 = w & 1;
  const int row0 = blockIdx.x * 64;
  if (tid < 256) biasl[tid] = bias[tid];

  const int arow = tid >> 3, aseg = tid & 7;  // A staging: row 0..63, 4-elem segment
  const int agrow = row0 + arow;
  float ainv = 1.f;
  if (IN_MODE >= 2) {
    float lt = lwA[agrow];
    if (IN_MODE == 2) lt += lwA[16384 + agrow];
    ainv = 1.f / lt;
  }

#define STAGEW(buf, ch1)                                                            \
  {                                                                                 \
    gld16((unsigned char*)Wl[buf] + tid * 16,                                       \
          Wb + (tid >> 2) * 256 + (ch1) * 32 + (tid & 3) * 8);                      \
    gld16((unsigned char*)Wl[buf] + (tid + 512) * 16,                               \
          Wb + ((tid + 512) >> 2) * 256 + (ch1) * 32 + (tid & 3) * 8);              \
  }
#define ACONV(dst, A4, M0, M1)                                                      \
  {                                                                                 \
    u32x2 _v;                                                                       \
    if (IN_MODE == 0) { _v[0] = pk2((A4).x, (A4).y); _v[1] = pk2((A4).z, (A4).w); } \
    else {                                                                          \
      float _e0 = bf2f((unsigned short)((M0)[0] & 0xFFFF));                         \
      float _e1 = bf2f((unsigned short)((M0)[0] >> 16));                            \
      float _e2 = bf2f((unsigned short)((M0)[1] & 0xFFFF));                         \
      float _e3 = bf2f((unsigned short)((M0)[1] >> 16));                            \
      if (IN_MODE == 2) {                                                           \
        _e0 += bf2f((unsigned short)((M1)[0] & 0xFFFF));                            \
        _e1 += bf2f((unsigned short)((M1)[0] >> 16));                               \
        _e2 += bf2f((unsigned short)((M1)[1] & 0xFFFF));                            \
        _e3 += bf2f((unsigned short)((M1)[1] >> 16));                               \
      }                                                                             \
      _v[0] = pk2(_e0 * ainv, _e1 * ainv); _v[1] = pk2(_e2 * ainv, _e3 * ainv);     \
    }                                                                               \
    *(u32x2*)(dst) = _v;                                                            \
  }

  {  // prologue: stage chunk 0
    STAGEW(0, 0);
    float4 a4; u32x2 m0, m1;
    if (IN_MODE == 0) {
      a4 = *(const float4*)((const float*)Ain + (size_t)agrow * 256 + aseg * 4);
    } else {
      const unsigned short* p0 = (const unsigned short*)Ain + (size_t)agrow * 256 + aseg * 4;
      m0 = *(const u32x2*)p0;
      if (IN_MODE == 2) m1 = *(const u32x2*)(p0 + 4194304);
    }
    ACONV(&Al[0][arow * 32 + aseg * 4], a4, m0, m1);
    __syncthreads();
  }

  f32x4 acc[8];
#pragma unroll
  for (int ct = 0; ct < 8; ++ct) acc[ct] = (f32x4){0.f, 0.f, 0.f, 0.f};

#pragma unroll 1
  for (int ch = 0; ch < 8; ++ch) {
    const int cur = ch & 1;
    const bool pre = (ch + 1 < 8);
    float4 a4; u32x2 m0, m1;
    if (pre) {  // early-issue next A + W loads
      const int ko = (ch + 1) * 32 + aseg * 4;
      if (IN_MODE == 0) {
        a4 = *(const float4*)((const float*)Ain + (size_t)agrow * 256 + ko);
      } else {
        const unsigned short* p0 = (const unsigned short*)Ain + (size_t)agrow * 256 + ko;
        m0 = *(const u32x2*)p0;
        if (IN_MODE == 2) m1 = *(const u32x2*)(p0 + 4194304);
      }
      STAGEW(1 - cur, ch + 1);
    }
    bf16x8 af = ldbf16(&Al[cur][(rt * 16 + c) * 32 + g * 8]);
#pragma unroll
    for (int ct = 0; ct < 8; ++ct) {
      const int j = ch2 * 128 + ct * 16 + c;
      bf16x8 wf = ldbf16(&Wl[cur][j * 32 + g * 8]);
      if (MODE == 1) acc[ct] = mfma16(af, wf, acc[ct]);   // lane&15 = col, regs = rows
      else           acc[ct] = mfma16(wf, af, acc[ct]);   // lane&15 = row, regs = cols
    }
    if (pre) ACONV(&Al[1 - cur][arow * 32 + aseg * 4], a4, m0, m1);
    __syncthreads();
  }

  // ---- epilogue
  if (MODE == 1) {  // V blocked: 4 consecutive n at fixed col
    unsigned short* vt = (unsigned short*)Cout;
    const int b = row0 >> 12, nb = (row0 & 4095) >> 6;
    const int nloc = rt * 16 + g * 4;
#pragma unroll
    for (int ct = 0; ct < 8; ++ct) {
      const int col = ch2 * 128 + ct * 16 + c;
      const float bv = biasl[col];
      us16x4 pk;
      pk[0] = f2bf(acc[ct][0] + bv); pk[1] = f2bf(acc[ct][1] + bv);
      pk[2] = f2bf(acc[ct][2] + bv); pk[3] = f2bf(acc[ct][3] + bv);
      *(us16x4*)(vt + (size_t)b * 1048576 + (size_t)nb * 16384 + col * 64 + nloc) = pk;
    }
  } else if (MODE == 0) {  // row-major bf16: 4 consecutive cols per lane
    unsigned short* q = (unsigned short*)Cout;
    const int row = row0 + rt * 16 + c;
#pragma unroll
    for (int ct = 0; ct < 8; ++ct) {
      const int col = ch2 * 128 + ct * 16 + g * 4;
      us16x4 pk;
      pk[0] = f2bf(acc[ct][0] + biasl[col + 0]);
      pk[1] = f2bf(acc[ct][1] + biasl[col + 1]);
      pk[2] = f2bf(acc[ct][2] + biasl[col + 2]);
      pk[3] = f2bf(acc[ct][3] + biasl[col + 3]);
      *(us16x4*)(q + (size_t)row * 256 + col) = pk;
    }
  } else {  // f32 row-major: float4 per lane
    float* o = (float*)Cout;
    const int row = row0 + rt * 16 + c;
#pragma unroll
    for (int ct = 0; ct < 8; ++ct) {
      const int col = ch2 * 128 + ct * 16 + g * 4;
      float4 ov;
      ov.x = acc[ct][0] + biasl[col + 0];
      ov.y = acc[ct][1] + biasl[col + 1];
      ov.z = acc[ct][2] + biasl[col + 2];
      ov.w = acc[ct][3] + biasl[col + 3];
      *(float4*)(o + (size_t)row * 256 + col) = ov;
    }
  }
#undef STAGEW
#undef ACONV
}

// ---------------- flash attention (R7, unchanged) ----------------
template <int NS>
__global__ __launch_bounds__(512, 2) void attn_k(const unsigned short* __restrict__ qg,
                                                 const unsigned short* __restrict__ kg,
                                                 const unsigned short* __restrict__ vg,
                                                 unsigned short* __restrict__ part,
                                                 float* __restrict__ lw) {
  __shared__ __align__(16) unsigned char smem[148480];
  const int tid = threadIdx.x, w = tid >> 6, l = tid & 63;
  const int l31 = l & 31, h5 = l >> 5;
  const int qt = w >> 1, hf = w & 1;   // QK role
  const int dh = w >> 1, qh = w & 1;   // PV role
  const int bid = blockIdx.x;
  const int b4 = bid & 3;
  const int s = (NS == 2) ? ((bid >> 2) & 1) : 0;
  const int qtl = (NS == 2) ? (bid >> 3) : (bid >> 2);
  const int q0 = qtl * 128;
  const int NT = (NS == 2) ? 32 : 64;

  const unsigned short* kb = kg + (size_t)b4 * 1048576 + (size_t)s * 524288;
  const unsigned short* vb = vg + (size_t)b4 * 1048576 + (size_t)s * 32 * 16384;

  bf16x8 qf[16];
  {
    const unsigned short* qp = qg + ((size_t)b4 * 4096 + q0 + qt * 32 + l31) * 256;
#pragma unroll
    for (int kst = 0; kst < 16; ++kst) qf[kst] = ldbf16(qp + kst * 16 + h5 * 8);
  }

  f32x16 o[4];
#pragma unroll
  for (int d = 0; d < 4; ++d)
#pragma unroll
    for (int r = 0; r < 16; ++r) o[d][r] = 0.f;
  float l_run = 0.f;

  int goffK[4], goffV[4];
#pragma unroll
  for (int i = 0; i < 4; ++i) {
    const int sl = i * 512 + tid;
    const int kk = sl >> 5, ch = sl & 31;
    goffK[i] = kk * 256 + ((ch ^ (kk & 31)) << 3);
    const int r = sl >> 4, p16 = sl & 15;
    const int x = p16 ^ (r & 15);
    goffV[i] = (2 * r + (x >> 3)) * 64 + ((x & 7) << 3);
  }
#define STAGE(buf, t1)                                                                   \
  {                                                                                      \
    const unsigned short* _ks = kb + (size_t)(t1) * 16384;                               \
    const unsigned short* _vs = vb + (size_t)(t1) * 16384;                               \
    _Pragma("unroll") for (int i = 0; i < 4; ++i)                                        \
        gld16(smem + (buf) * 32768 + i * 8192 + w * 1024, _ks + goffK[i]);               \
    _Pragma("unroll") for (int i = 0; i < 4; ++i)                                        \
        gld16(smem + 65536 + (buf) * 32768 + i * 8192 + w * 1024, _vs + goffV[i]);       \
  }

  STAGE(0, 0);
  __syncthreads();

  const float alpha = 0.09016844f;  // log2(e)/16
  unsigned char* Pq = smem + 131072 + qt * 4096;
  const int kkr = hf * 32 + l31;

#pragma unroll 1
  for (int t = 0; t < NT; ++t) {
    const int cur = t & 1;
    if (t + 1 < NT) STAGE(1 - cur, t + 1);

    const unsigned char* Kc = smem + cur * 32768 + kkr * 512;
    f32x16 sa, sb;
#pragma unroll
    for (int r = 0; r < 16; ++r) { sa[r] = 0.f; sb[r] = 0.f; }
    __builtin_amdgcn_s_setprio(1);
#pragma unroll
    for (int kst = 0; kst < 16; ++kst) {
      bf16x8 kf = ldbf16(Kc + (((kst * 2 + h5) ^ l31) << 4));
      if (kst & 1) sb = mfma32(kf, qf[kst], sb);
      else         sa = mfma32(kf, qf[kst], sa);
    }
    __builtin_amdgcn_s_setprio(0);

    float p[16];
#pragma unroll
    for (int r = 0; r < 16; ++r) p[r] = exp2f((sa[r] + sb[r]) * alpha);
    float ls = ((p[0] + p[1]) + (p[2] + p[3])) + ((p[4] + p[5]) + (p[6] + p[7])) +
               (((p[8] + p[9]) + (p[10] + p[11])) + ((p[12] + p[13]) + (p[14] + p[15])));
    ls += __shfl_xor(ls, 32);
    l_run += ls;

    unsigned u[8];
#pragma unroll
    for (int i = 0; i < 8; ++i) u[i] = cvtpk(p[2 * i], p[2 * i + 1]);
#pragma unroll
    for (int j = 0; j < 4; ++j) {
      u32x2 dv; dv[0] = u[2 * j]; dv[1] = u[2 * j + 1];
      *(u32x2*)(Pq + l31 * 128 + (((j + 4 * hf) ^ (l31 & 7)) << 4) + h5 * 8) = dv;
    }

    asm volatile("s_waitcnt lgkmcnt(0)\n\ts_barrier" ::: "memory");
    __builtin_amdgcn_sched_barrier(0);

    const unsigned char* Vc = smem + 65536 + cur * 32768;
    bf16x8 va[8];
#pragma unroll
    for (int dd = 0; dd < 2; ++dd) {
      const int dm = dh * 64 + dd * 32 + l31;
      const int rr = dm >> 1;
      const unsigned char* Vr = Vc + rr * 256;
      const int xb = (dm & 1) * 8;
#pragma unroll
      for (int kst = 0; kst < 4; ++kst)
        va[dd * 4 + kst] = ldbf16(Vr + (((xb + kst * 2 + h5) ^ (rr & 15)) << 4));
    }
    __builtin_amdgcn_s_setprio(1);
#pragma unroll
    for (int qq = 0; qq < 2; ++qq) {
      const unsigned char* Pr = smem + 131072 + (qh * 2 + qq) * 4096;
      bf16x8 pb[4];
#pragma unroll
      for (int kst = 0; kst < 4; ++kst)
        pb[kst] = ldbf16(Pr + l31 * 128 + (((kst * 2 + h5) ^ (l31 & 7)) << 4));
#pragma unroll
      for (int dd = 0; dd < 2; ++dd)
#pragma unroll
        for (int kst = 0; kst < 4; ++kst)
          o[dd * 2 + qq] = mfma32(va[dd * 4 + kst], pb[kst], o[dd * 2 + qq]);
    }
    __builtin_amdgcn_s_setprio(0);

    __syncthreads();
  }
#undef STAGE

  float* Lb = (float*)(smem + 147456);
  if (l < 32) Lb[(qt * 2 + hf) * 32 + l31] = l_run;
  __syncthreads();

  unsigned char* T = smem + w * 16384;
#pragma unroll
  for (int dd = 0; dd < 2; ++dd)
#pragma unroll
    for (int qq = 0; qq < 2; ++qq)
#pragma unroll
      for (int rg = 0; rg < 4; ++rg) {
        f32x4 wv;
        wv[0] = o[dd * 2 + qq][4 * rg + 0]; wv[1] = o[dd * 2 + qq][4 * rg + 1];
        wv[2] = o[dd * 2 + qq][4 * rg + 2]; wv[3] = o[dd * 2 + qq][4 * rg + 3];
        const int qloc = qq * 32 + l31;
        const int c16 = dd * 8 + rg * 2 + h5;
        *(f32x4*)(T + qloc * 256 + ((c16 ^ (qloc & 15)) << 4)) = wv;
      }
  asm volatile("s_waitcnt lgkmcnt(0)" ::: "memory");
  __builtin_amdgcn_sched_barrier(0);
  {
    const int qloc = l;
    f32x4 rv[16];
#pragma unroll
    for (int c16 = 0; c16 < 16; ++c16)
      rv[c16] = *(const f32x4*)(T + qloc * 256 + ((c16 ^ (qloc & 15)) << 4));
    unsigned short* op = part + (size_t)s * 4194304 +
                         ((size_t)b4 * 4096 + q0 + qh * 64 + qloc) * 256 + dh * 64;
#pragma unroll
    for (int i = 0; i < 8; ++i) {
      u32x4 ov;
      ov[0] = pk2(rv[2 * i][0], rv[2 * i][1]);
      ov[1] = pk2(rv[2 * i][2], rv[2 * i][3]);
      ov[2] = pk2(rv[2 * i + 1][0], rv[2 * i + 1][1]);
      ov[3] = pk2(rv[2 * i + 1][2], rv[2 * i + 1][3]);
      *(u32x4*)(op + i * 8) = ov;
    }
  }
  if (hf == 0 && l < 32) {
    const float lt = Lb[(qt * 2) * 32 + l31] + Lb[(qt * 2 + 1) * 32 + l31];
    lw[(size_t)s * 16384 + (size_t)b4 * 4096 + q0 + qt * 32 + l31] = lt;
  }
}

extern "C" void kernel_launch(void* const* d_in, const int* in_sizes, int n_in,
                              void* d_out, int out_size, void* d_ws, size_t ws_size,
                              hipStream_t stream) {
  (void)in_sizes; (void)n_in; (void)out_size;
  const float* desc0 = (const float*)d_in[0];
  const float* desc1 = (const float*)d_in[1];
  const float* Wq = (const float*)d_in[2];
  const float* bq = (const float*)d_in[3];
  const float* Wk = (const float*)d_in[4];
  const float* bk = (const float*)d_in[5];
  const float* Wv = (const float*)d_in[6];
  const float* bv = (const float*)d_in[7];
  const float* Wo = (const float*)d_in[8];
  const float* bo = (const float*)d_in[9];

  unsigned char* ws = (unsigned char*)d_ws;
  unsigned short* qw = (unsigned short*)(ws);
  unsigned short* kw = (unsigned short*)(ws + 8388608);
  unsigned short* vw = (unsigned short*)(ws + 16777216);
  unsigned short* part = (unsigned short*)(ws + 25165824);

  const bool two = (ws_size >= 42598400ull);
  float* lwp;
  unsigned short* wbf;
  if (two) {
    lwp = (float*)(ws + 41943040);
    wbf = (unsigned short*)(ws + 42074112);
  } else {
    lwp = (float*)(ws + 33554432);
    wbf = (unsigned short*)(ws + 33685504);
  }

  wconv_k<<<128, 256, 0, stream>>>(Wq, Wk, Wv, Wo, wbf);
  proj_k<0, 0><<<256, 512, 0, stream>>>(desc0, wbf + 0 * 65536, bq, qw, nullptr);
  proj_k<0, 0><<<256, 512, 0, stream>>>(desc1, wbf + 1 * 65536, bk, kw, nullptr);
  proj_k<0, 1><<<256, 512, 0, stream>>>(desc1, wbf + 2 * 65536, bv, vw, nullptr);
  if (two) {
    attn_k<2><<<256, 512, 0, stream>>>(qw, kw, vw, part, lwp);
    proj_k<2, 2><<<256, 512, 0, stream>>>(part, wbf + 3 * 65536, bo, (float*)d_out, lwp);
  } else {
    attn_k<1><<<128, 512, 0, stream>>>(qw, kw, vw, part, lwp);
    proj_k<3, 2><<<256, 512, 0, stream>>>(part, wbf + 3 * 65536, bo, (float*)d_out, lwp);
  }
}